// Round 1
// baseline (213.998 us; speedup 1.0000x reference)
//
#include <hip/hip_runtime.h>
#include <math.h>

#define TILE 32
#define K 11
#define PAD 5
#define IN_T (TILE + 2 * PAD)   // 42
#define BLOCK 256

__global__ __launch_bounds__(BLOCK) void ssim_tile_kernel(
    const float* __restrict__ img1, const float* __restrict__ img2,
    const float* __restrict__ window, float* __restrict__ partials,
    int H, int W)
{
    __shared__ float s1[IN_T][IN_T + 1];
    __shared__ float s2[IN_T][IN_T + 1];
    __shared__ float hA[IN_T][TILE];
    __shared__ float hB[IN_T][TILE];
    __shared__ float hAA[IN_T][TILE];
    __shared__ float hBB[IN_T][TILE];
    __shared__ float hAB[IN_T][TILE];
    __shared__ float wl[K];
    __shared__ float red[BLOCK / 64];

    const float C1 = 0.01f * 0.01f;
    const float C2 = 0.03f * 0.03f;

    const int tid = threadIdx.x;

    // Derive separable 1D weights from the 2D window: win2d = a (outer) a, sum(a)=1.
    // a[i] = win2d[i][5] / sqrt(win2d[5][5]).  (window layout [C,1,K,K]; all C identical)
    if (tid < K) {
        float c = sqrtf(window[5 * K + 5]);
        wl[tid] = window[tid * K + 5] / c;
    }

    const int plane = blockIdx.z;
    const size_t plane_off = (size_t)plane * H * W;
    const float* __restrict__ p1 = img1 + plane_off;
    const float* __restrict__ p2 = img2 + plane_off;
    const int ox = blockIdx.x * TILE - PAD;
    const int oy = blockIdx.y * TILE - PAD;

    // --- stage halo tiles into LDS (zero-padded, matches conv zero padding) ---
    for (int i = tid; i < IN_T * IN_T; i += BLOCK) {
        int r = i / IN_T, c = i - r * IN_T;
        int gy = oy + r, gx = ox + c;
        bool ok = (gy >= 0) & (gy < H) & (gx >= 0) & (gx < W);
        size_t gidx = (size_t)gy * W + gx;
        s1[r][c] = ok ? p1[gidx] : 0.f;
        s2[r][c] = ok ? p2[gidx] : 0.f;
    }
    __syncthreads();

    // --- horizontal pass: 5 fused quantities over 42 rows x 32 cols ---
    for (int i = tid; i < IN_T * TILE; i += BLOCK) {
        int r = i / TILE, c = i - r * TILE;
        float a = 0.f, b = 0.f, aa = 0.f, bb = 0.f, ab = 0.f;
        #pragma unroll
        for (int k = 0; k < K; ++k) {
            float w = wl[k];
            float x = s1[r][c + k];
            float y = s2[r][c + k];
            a  += w * x;
            b  += w * y;
            aa += w * x * x;
            bb += w * y * y;
            ab += w * x * y;
        }
        hA[r][c] = a; hB[r][c] = b;
        hAA[r][c] = aa; hBB[r][c] = bb; hAB[r][c] = ab;
    }
    __syncthreads();

    // --- vertical pass + SSIM map + per-thread accumulation ---
    float acc = 0.f;
    for (int i = tid; i < TILE * TILE; i += BLOCK) {
        int r = i / TILE, c = i - r * TILE;
        float mu1 = 0.f, mu2 = 0.f, saa = 0.f, sbb = 0.f, sab = 0.f;
        #pragma unroll
        for (int k = 0; k < K; ++k) {
            float w = wl[k];
            mu1 += w * hA[r + k][c];
            mu2 += w * hB[r + k][c];
            saa += w * hAA[r + k][c];
            sbb += w * hBB[r + k][c];
            sab += w * hAB[r + k][c];
        }
        float mu1sq = mu1 * mu1;
        float mu2sq = mu2 * mu2;
        float mu12  = mu1 * mu2;
        float sig1  = saa - mu1sq;
        float sig2  = sbb - mu2sq;
        float sig12 = sab - mu12;
        float num = (2.f * mu12 + C1) * (2.f * sig12 + C2);
        float den = (mu1sq + mu2sq + C1) * (sig1 + sig2 + C2);
        acc += num / den;
    }

    // --- block reduction: wave shuffle then LDS across 4 waves ---
    #pragma unroll
    for (int off = 32; off > 0; off >>= 1)
        acc += __shfl_down(acc, off, 64);
    int wave = tid >> 6;
    if ((tid & 63) == 0) red[wave] = acc;
    __syncthreads();
    if (tid == 0) {
        float s = red[0] + red[1] + red[2] + red[3];
        int bid = (blockIdx.z * gridDim.y + blockIdx.y) * gridDim.x + blockIdx.x;
        partials[bid] = s;
    }
}

__global__ __launch_bounds__(BLOCK) void ssim_reduce_kernel(
    const float* __restrict__ partials, float* __restrict__ out,
    int n, double inv_count)
{
    __shared__ double red[BLOCK / 64];
    double s = 0.0;
    for (int i = threadIdx.x; i < n; i += BLOCK) s += (double)partials[i];
    #pragma unroll
    for (int off = 32; off > 0; off >>= 1)
        s += __shfl_down(s, off, 64);
    int wave = threadIdx.x >> 6;
    if ((threadIdx.x & 63) == 0) red[wave] = s;
    __syncthreads();
    if (threadIdx.x == 0) {
        double total = red[0] + red[1] + red[2] + red[3];
        out[0] = (float)(1.0 - total * inv_count);
    }
}

extern "C" void kernel_launch(void* const* d_in, const int* in_sizes, int n_in,
                              void* d_out, int out_size, void* d_ws, size_t ws_size,
                              hipStream_t stream) {
    const float* img1   = (const float*)d_in[0];
    const float* img2   = (const float*)d_in[1];
    const float* window = (const float*)d_in[2];
    float* out = (float*)d_out;
    float* partials = (float*)d_ws;

    const int N = 16, C = 9, H = 256, W = 256;
    const int planes = N * C;                 // 144
    const int tx = W / TILE, ty = H / TILE;   // 8 x 8
    const int nblocks = tx * ty * planes;     // 9216

    dim3 grid(tx, ty, planes);
    ssim_tile_kernel<<<grid, BLOCK, 0, stream>>>(img1, img2, window, partials, H, W);

    const double inv_count = 1.0 / ((double)planes * H * W);
    ssim_reduce_kernel<<<1, BLOCK, 0, stream>>>(partials, out, nblocks, inv_count);
}

// Round 2
// 166.841 us; speedup vs baseline: 1.2826x; 1.2826x over previous
//
#include <hip/hip_runtime.h>
#include <math.h>

#define Wd 256
#define Hd 256
#define KW 11
#define PAD 5
#define OUT_R 32              // output rows per block (band)
#define NCHUNK 4              // 4*11 = 44 h-rows staged >= OUT_R + 10
#define ROWW (Wd + 2 * PAD)   // 266
#define BLOCK 256

__device__ __forceinline__ float rfl(float v) {
    return __int_as_float(__builtin_amdgcn_readfirstlane(__float_as_int(v)));
}

// One block = one 32-row band of one (n,c) plane. 256 threads = 1 thread/column.
// Horizontal 11-tap pass reads an LDS-staged row (stride-1, conflict-free);
// vertical 11-tap pass runs in a register ring buffer (static indices via
// 11-row chunks: local h-row i = ch*11+j  =>  ring slot = j).
__global__ __launch_bounds__(BLOCK) void ssim_band_kernel(
    const float* __restrict__ img1, const float* __restrict__ img2,
    const float* __restrict__ window, float* __restrict__ partials)
{
    __shared__ float s1[KW][ROWW];
    __shared__ float s2[KW][ROWW];   // 2*11*266*4 = 23.4 KB
    __shared__ float red[BLOCK / 64];

    const float C1 = 1e-4f, C2 = 9e-4f;
    const int t = threadIdx.x;
    const int band = blockIdx.x;     // 0..7
    const int plane = blockIdx.y;    // 0..143
    const float* __restrict__ p1 = img1 + (size_t)plane * (Hd * Wd);
    const float* __restrict__ p2 = img2 + (size_t)plane * (Hd * Wd);

    // Separable 1D weights from 2D window (win2d = a outer a, sum a = 1);
    // wave-uniform -> pin to SGPRs via readfirstlane.
    float wl[KW];
    {
        float c = sqrtf(window[5 * KW + 5]);
        #pragma unroll
        for (int k = 0; k < KW; ++k)
            wl[k] = rfl(window[k * KW + 5] / c);
    }

    float rA[KW], rB[KW], rAA[KW], rBB[KW], rAB[KW];
    float acc = 0.f;
    const int ghbase = band * OUT_R - PAD;  // image row of local h index 0

    #pragma unroll 1
    for (int ch = 0; ch < NCHUNK; ++ch) {
        __syncthreads();  // previous chunk's readers done before overwrite
        // --- stage 11 rows (coalesced, clamped row + select for zero-pad) ---
        #pragma unroll
        for (int j = 0; j < KW; ++j) {
            int g = ghbase + ch * KW + j;
            bool ok = (g >= 0) & (g < Hd);
            int gc = min(max(g, 0), Hd - 1);
            float v1 = p1[gc * Wd + t];
            float v2 = p2[gc * Wd + t];
            s1[j][PAD + t] = ok ? v1 : 0.f;
            s2[j][PAD + t] = ok ? v2 : 0.f;
        }
        if (t < 2 * PAD) {
            int c = (t < PAD) ? t : (Wd + t);  // 0..4 and 261..265
            #pragma unroll
            for (int j = 0; j < KW; ++j) { s1[j][c] = 0.f; s2[j][c] = 0.f; }
        }
        __syncthreads();

        // --- 11 h-rows: horizontal pass into ring slot j, emit output when full ---
        #pragma unroll
        for (int j = 0; j < KW; ++j) {
            float a = 0.f, b = 0.f, aa = 0.f, bb = 0.f, ab = 0.f;
            #pragma unroll
            for (int k = 0; k < KW; ++k) {
                float x = s1[j][t + k];
                float y = s2[j][t + k];
                float tx = wl[k] * x;
                float ty = wl[k] * y;
                a += tx; b += ty;
                aa += tx * x; bb += ty * y; ab += tx * y;
            }
            rA[j] = a; rB[j] = b; rAA[j] = aa; rBB[j] = bb; rAB[j] = ab;

            const int i = ch * KW + j;             // local h index (uniform)
            if (i >= 10 && i < OUT_R + 10) {       // output row o = band*OUT_R + i - 10
                float mu1 = 0.f, mu2 = 0.f, saa = 0.f, sbb = 0.f, sab = 0.f;
                #pragma unroll
                for (int m = 0; m < KW; ++m) {     // ring slot for h-row (o-5+m)
                    const int s = (j + 1 + m) % KW;  // static per (j,m)
                    float w = wl[m];
                    mu1 += w * rA[s]; mu2 += w * rB[s];
                    saa += w * rAA[s]; sbb += w * rBB[s]; sab += w * rAB[s];
                }
                float mu1sq = mu1 * mu1, mu2sq = mu2 * mu2, mu12 = mu1 * mu2;
                float num = (2.f * mu12 + C1) * (2.f * (sab - mu12) + C2);
                float den = (mu1sq + mu2sq + C1)
                          * ((saa - mu1sq) + (sbb - mu2sq) + C2);
                acc += num * __builtin_amdgcn_rcpf(den);
            }
        }
    }

    // --- block reduction ---
    #pragma unroll
    for (int off = 32; off > 0; off >>= 1)
        acc += __shfl_down(acc, off, 64);
    int wave = t >> 6;
    if ((t & 63) == 0) red[wave] = acc;
    __syncthreads();
    if (t == 0)
        partials[plane * gridDim.x + band] = red[0] + red[1] + red[2] + red[3];
}

__global__ __launch_bounds__(BLOCK) void ssim_reduce_kernel(
    const float* __restrict__ partials, float* __restrict__ out,
    int n, double inv_count)
{
    __shared__ double red[BLOCK / 64];
    double s = 0.0;
    for (int i = threadIdx.x; i < n; i += BLOCK) s += (double)partials[i];
    #pragma unroll
    for (int off = 32; off > 0; off >>= 1)
        s += __shfl_down(s, off, 64);
    int wave = threadIdx.x >> 6;
    if ((threadIdx.x & 63) == 0) red[wave] = s;
    __syncthreads();
    if (threadIdx.x == 0) {
        double total = red[0] + red[1] + red[2] + red[3];
        out[0] = (float)(1.0 - total * inv_count);
    }
}

extern "C" void kernel_launch(void* const* d_in, const int* in_sizes, int n_in,
                              void* d_out, int out_size, void* d_ws, size_t ws_size,
                              hipStream_t stream) {
    const float* img1   = (const float*)d_in[0];
    const float* img2   = (const float*)d_in[1];
    const float* window = (const float*)d_in[2];
    float* out = (float*)d_out;
    float* partials = (float*)d_ws;

    const int planes = 16 * 9;            // 144
    const int bands = Hd / OUT_R;         // 8
    const int nblocks = planes * bands;   // 1152

    dim3 grid(bands, planes);
    ssim_band_kernel<<<grid, BLOCK, 0, stream>>>(img1, img2, window, partials);

    const double inv_count = 1.0 / ((double)planes * Hd * Wd);
    ssim_reduce_kernel<<<1, BLOCK, 0, stream>>>(partials, out, nblocks, inv_count);
}

// Round 3
// 138.078 us; speedup vs baseline: 1.5498x; 1.2083x over previous
//
#include <hip/hip_runtime.h>
#include <math.h>

#define Wd 256
#define Hd 256
#define KW 11
#define PAD 5
#define OUT_R 32              // output rows per block (band)
#define NCHUNK 4              // 4*11 = 44 h-rows staged >= OUT_R + 10
#define LPAD 8                // left pad (floats) so data starts 16B-aligned
#define ROWW 272              // LPAD + 256 + 8; stride 1088 B = 68*16 (16B-aligned rows)
#define BLOCK 256

__device__ __forceinline__ float rfl(float v) {
    return __int_as_float(__builtin_amdgcn_readfirstlane(__float_as_int(v)));
}

// One block = one 32-row band of one (n,c) plane. 256 threads = 1 thread/column.
// Horizontal 11-tap pass reads LDS-staged rows (stride-1, conflict-free);
// vertical 11-tap pass runs in a 4-channel register ring buffer with static
// indices (local h-row i = ch*11+j  =>  ring slot = j).
// Channels: A=conv(x), B=conv(y), Q=conv(x^2+y^2), P=conv(x*y) — SSIM only
// needs sigma1^2 + sigma2^2, never the two separately.
__global__ __launch_bounds__(BLOCK, 4) void ssim_band_kernel(
    const float* __restrict__ img1, const float* __restrict__ img2,
    const float* __restrict__ window, float* __restrict__ partials)
{
    __shared__ __align__(16) float s1[KW][ROWW];
    __shared__ __align__(16) float s2[KW][ROWW];   // 2*11*272*4 = 23.9 KB
    __shared__ float red[BLOCK / 64];

    const float C1 = 1e-4f, C2 = 9e-4f;
    const int t = threadIdx.x;
    const int band = blockIdx.x;     // 0..7
    const int plane = blockIdx.y;    // 0..143
    const float* __restrict__ p1 = img1 + (size_t)plane * (Hd * Wd);
    const float* __restrict__ p2 = img2 + (size_t)plane * (Hd * Wd);

    // Separable 1D weights from 2D window (win2d = a outer a, sum a = 1);
    // wave-uniform -> pin to SGPRs via readfirstlane.
    float wl[KW];
    {
        float c = sqrtf(window[5 * KW + 5]);
        #pragma unroll
        for (int k = 0; k < KW; ++k)
            wl[k] = rfl(window[k * KW + 5] / c);
    }

    // Zero the halo cells once (staging never writes idx 3..7 / 264..268).
    // Taps read idx t+3 .. t+13: col -5..-1 -> idx 3..7, col 256..260 -> 264..268.
    if (t < 110) {
        int r = t / 10, c = t % 10;
        int idx = (c < PAD) ? (3 + c) : (259 + c);
        s1[r][idx] = 0.f;
        s2[r][idx] = 0.f;
    }

    float rA[KW], rB[KW], rQ[KW], rP[KW];
    float acc = 0.f;
    const int ghbase = band * OUT_R - PAD;  // image row of local h index 0

    #pragma unroll 1
    for (int ch = 0; ch < NCHUNK; ++ch) {
        __syncthreads();  // previous chunk's readers done before overwrite
        // --- stage 11 rows x 2 images, float4 loads + b128 LDS writes ---
        {
            const int gb = ghbase + ch * KW;
            #pragma unroll 1
            for (int i = t; i < KW * 64; i += BLOCK) {
                int r = i >> 6, q = i & 63;
                int g = gb + r;
                bool ok = (g >= 0) & (g < Hd);
                int gc = min(max(g, 0), Hd - 1);
                float4 v1 = *(const float4*)(p1 + (size_t)gc * Wd + 4 * q);
                float4 v2 = *(const float4*)(p2 + (size_t)gc * Wd + 4 * q);
                if (!ok) { v1 = make_float4(0.f, 0.f, 0.f, 0.f);
                           v2 = make_float4(0.f, 0.f, 0.f, 0.f); }
                *(float4*)&s1[r][LPAD + 4 * q] = v1;
                *(float4*)&s2[r][LPAD + 4 * q] = v2;
            }
        }
        __syncthreads();

        // --- 11 h-rows: horizontal pass into ring slot j, emit when full ---
        #pragma unroll
        for (int j = 0; j < KW; ++j) {
            float a = 0.f, b = 0.f, qq = 0.f, pp = 0.f;
            #pragma unroll
            for (int k = 0; k < KW; ++k) {
                float w = wl[k];
                float x = s1[j][t + 3 + k];
                float y = s2[j][t + 3 + k];
                a = fmaf(w, x, a);
                b = fmaf(w, y, b);
                float xy = x * y;
                float ss = fmaf(y, y, x * x);
                pp = fmaf(w, xy, pp);
                qq = fmaf(w, ss, qq);
            }
            rA[j] = a; rB[j] = b; rQ[j] = qq; rP[j] = pp;

            const int i = ch * KW + j;             // local h index (uniform)
            if (i >= 10 && i < OUT_R + 10) {       // output row o = band*OUT_R + i - 10
                float mu1 = 0.f, mu2 = 0.f, sq = 0.f, sp = 0.f;
                #pragma unroll
                for (int m = 0; m < KW; ++m) {     // ring slot for h-row (o-5+m)
                    const int s = (j + 1 + m) % KW;  // static per (j,m)
                    float w = wl[m];
                    mu1 = fmaf(w, rA[s], mu1);
                    mu2 = fmaf(w, rB[s], mu2);
                    sq  = fmaf(w, rQ[s], sq);
                    sp  = fmaf(w, rP[s], sp);
                }
                float mu1sq = mu1 * mu1, mu2sq = mu2 * mu2, mu12 = mu1 * mu2;
                float musum = mu1sq + mu2sq;
                float num = (2.f * mu12 + C1) * (2.f * (sp - mu12) + C2);
                float den = (musum + C1) * ((sq - musum) + C2);
                acc += num * __builtin_amdgcn_rcpf(den);
            }
        }
    }

    // --- block reduction ---
    #pragma unroll
    for (int off = 32; off > 0; off >>= 1)
        acc += __shfl_down(acc, off, 64);
    int wave = t >> 6;
    if ((t & 63) == 0) red[wave] = acc;
    __syncthreads();
    if (t == 0)
        partials[plane * gridDim.x + band] = red[0] + red[1] + red[2] + red[3];
}

__global__ __launch_bounds__(BLOCK) void ssim_reduce_kernel(
    const float* __restrict__ partials, float* __restrict__ out,
    int n, double inv_count)
{
    __shared__ double red[BLOCK / 64];
    double s = 0.0;
    for (int i = threadIdx.x; i < n; i += BLOCK) s += (double)partials[i];
    #pragma unroll
    for (int off = 32; off > 0; off >>= 1)
        s += __shfl_down(s, off, 64);
    int wave = threadIdx.x >> 6;
    if ((threadIdx.x & 63) == 0) red[wave] = s;
    __syncthreads();
    if (threadIdx.x == 0) {
        double total = red[0] + red[1] + red[2] + red[3];
        out[0] = (float)(1.0 - total * inv_count);
    }
}

extern "C" void kernel_launch(void* const* d_in, const int* in_sizes, int n_in,
                              void* d_out, int out_size, void* d_ws, size_t ws_size,
                              hipStream_t stream) {
    const float* img1   = (const float*)d_in[0];
    const float* img2   = (const float*)d_in[1];
    const float* window = (const float*)d_in[2];
    float* out = (float*)d_out;
    float* partials = (float*)d_ws;

    const int planes = 16 * 9;            // 144
    const int bands = Hd / OUT_R;         // 8
    const int nblocks = planes * bands;   // 1152

    dim3 grid(bands, planes);
    ssim_band_kernel<<<grid, BLOCK, 0, stream>>>(img1, img2, window, partials);

    const double inv_count = 1.0 / ((double)planes * Hd * Wd);
    ssim_reduce_kernel<<<1, BLOCK, 0, stream>>>(partials, out, nblocks, inv_count);
}